// Round 9
// baseline (3942.188 us; speedup 1.0000x reference)
//
#include <hip/hip_runtime.h>
#include <cstdint>
#include <cstddef>

// ---------------------------------------------------------------------------
// MultiLayerAttentionModel on MI355X (gfx950), bf16 MFMA pipeline, round 16.
// Round 15's LN2 fold with fixed LAYOUT: z gets a dense [131072][576] buffer
// (inside the shrunken qkv region); qkv is now Q||K only, stride 1024. R15's
// z-in-dead-V-columns (stride 1664) wrecked A-tile L2 locality for the QKV
// GEMM (FETCH +14MB, MfmaUtil 30->24.5, +75us/dispatch). All strides dense.
// ---------------------------------------------------------------------------

typedef unsigned short u16;
typedef float f32x4 __attribute__((ext_vector_type(4)));
typedef unsigned short u16x8 __attribute__((ext_vector_type(8)));

#define P 576
#define NQK 1664
#define QKLD 1024
#define ZLD 576
#define VTROWS 514
#define KVLD 640

__device__ __forceinline__ float bf2f(u16 s) {
    union { unsigned u; float f; } v; v.u = ((unsigned)s) << 16; return v.f;
}
__device__ __forceinline__ u16 f2bf(float f) {
    union { float f; unsigned u; } v; v.f = f;
    unsigned r = v.u + 0x7FFF + ((v.u >> 16) & 1);
    return (u16)(r >> 16);
}
__device__ __forceinline__ float wredsum(float v) {
#pragma unroll
    for (int o = 32; o > 0; o >>= 1) v += __shfl_xor(v, o, 64);
    return v;
}
__device__ __forceinline__ f32x4 mfma_16x16x32_bf16(u16x8 a, u16x8 b, f32x4 c) {
    asm volatile("v_mfma_f32_16x16x32_bf16 %0, %1, %2, %0"
                 : "+v"(c) : "v"(a), "v"(b));
    return c;
}
__device__ __forceinline__ void gload_lds16(const u16* g, u16* l) {
    __builtin_amdgcn_global_load_lds(
        (const __attribute__((address_space(1))) void*)g,
        (__attribute__((address_space(3))) void*)l, 16, 0, 0);
}

// ---------------------------------------------------------------------------
__global__ __launch_bounds__(256) void k_build_tokens(
    const float* __restrict__ xs, const float* __restrict__ ys,
    const float* __restrict__ qx, u16* __restrict__ tok,
    float* __restrict__ meanb, float* __restrict__ rstdb)
{
    long row = (long)blockIdx.x * 4 + (threadIdx.x >> 6);
    int lane = threadIdx.x & 63;
    int b = (int)(row >> 11), n = (int)(row & 2047);
    const float* src = (n < 2047) ? xs + ((long)(b * 2047 + n)) * 512
                                  : qx + (long)b * 512;
    float4 f0 = *(const float4*)(src + lane * 8);
    float4 f1 = *(const float4*)(src + lane * 8 + 4);
    float y = (n < 2047) ? ys[(long)b * 2047 + n] : 0.f;
    float v[8] = {f0.x, f0.y, f0.z, f0.w, f1.x, f1.y, f1.z, f1.w};
    float s = 0.f, sq = 0.f;
#pragma unroll
    for (int j = 0; j < 8; j++) { s += v[j]; sq += v[j] * v[j]; }
    if (lane == 0) { s += y; sq += y * y; }
    s = wredsum(s); sq = wredsum(sq);
    u16x8 o;
#pragma unroll
    for (int j = 0; j < 8; j++) o[j] = f2bf(v[j]);
    *(u16x8*)(tok + row * P + lane * 8) = o;
    if (lane < 8) {
        u16x8 z8 = {0,0,0,0,0,0,0,0};
        if (lane == 0) z8[0] = f2bf(y);
        *(u16x8*)(tok + row * P + 512 + lane * 8) = z8;
    }
    if (lane == 0) {
        float m = s * (1.f / 513.f);
        float var = sq * (1.f / 513.f) - m * m;
        meanb[row] = m;
        rstdb[row] = 1.f / sqrtf(var + 1e-5f);
    }
}

// wcat[l][r][t] = W[r][t] * ln1w[l][t] * (l>0 ? ln2w[l-1][t] : 1)
__global__ __launch_bounds__(256) void k_prep_wcat(
    const float* __restrict__ wq, const float* __restrict__ wk,
    const float* __restrict__ wv, const float* __restrict__ ln1w,
    const float* __restrict__ ln2w, u16* __restrict__ wcat)
{
    long idx = (long)blockIdx.x * 256 + threadIdx.x;
    if (idx >= 4L * NQK * P) return;
    int t = (int)(idx % P);
    long rem = idx / P;
    int r = (int)(rem % NQK);
    int l = (int)(rem / NQK);
    float v = 0.f;
    if (t < 513) {
        float wsc = ln1w[l * 513 + t];
        if (l > 0) wsc *= ln2w[(l - 1) * 513 + t];
        if (r < 512)       v = wq[((long)l * 512 + r) * 513 + t] * wsc;
        else if (r < 1024) v = wk[((long)l * 512 + (r - 512)) * 513 + t] * wsc;
        else if (r < 1537) v = wv[((long)l * 513 + (r - 1024)) * 513 + t] * wsc;
    }
    wcat[idx] = f2bf(v);
}

__global__ __launch_bounds__(256) void k_prep_wo(
    const float* __restrict__ wo, u16* __restrict__ wop)
{
    long idx = (long)blockIdx.x * 256 + threadIdx.x;
    if (idx >= 4L * P * P) return;
    int u = (int)(idx % P);
    long rem = idx / P;
    int t = (int)(rem % P);
    int l = (int)(rem / P);
    float v = (t < 513 && u < 513) ? wo[((long)l * 513 + t) * 513 + u] : 0.f;
    wop[idx] = f2bf(v);
}

// xcol4[(l*NQK+r)*4] = { Sum g2p*g1*W, Sum b2p*g1*W, Sum g1*W, Sum b1*W }
__global__ __launch_bounds__(256) void k_prep_sums(
    const float* __restrict__ wq, const float* __restrict__ wk,
    const float* __restrict__ wv, const float* __restrict__ ln1w,
    const float* __restrict__ ln1b, const float* __restrict__ ln2w,
    const float* __restrict__ ln2b, float* __restrict__ xcol4)
{
    int id = blockIdx.x * 4 + (threadIdx.x >> 6);
    int lane = threadIdx.x & 63;
    int l = id / NQK, r = id % NQK;
    float a21 = 0.f, b2g = 0.f, a1 = 0.f, b1 = 0.f;
    for (int t = lane; t < 513; t += 64) {
        float wc = 0.f;
        if (r < 512)       wc = wq[((long)l * 512 + r) * 513 + t];
        else if (r < 1024) wc = wk[((long)l * 512 + (r - 512)) * 513 + t];
        else if (r < 1537) wc = wv[((long)l * 513 + (r - 1024)) * 513 + t];
        float g1 = ln1w[l * 513 + t], bb1 = ln1b[l * 513 + t];
        float g2 = (l > 0) ? ln2w[(l - 1) * 513 + t] : 0.f;
        float b2 = (l > 0) ? ln2b[(l - 1) * 513 + t] : 0.f;
        a1  += g1 * wc;
        b1  += bb1 * wc;
        a21 += g2 * g1 * wc;
        b2g += b2 * g1 * wc;
    }
    a21 = wredsum(a21); b2g = wredsum(b2g);
    a1 = wredsum(a1); b1 = wredsum(b1);
    if (lane == 0) {
        xcol4[(long)id * 4 + 0] = a21;
        xcol4[(long)id * 4 + 1] = b2g;
        xcol4[(long)id * 4 + 2] = a1;
        xcol4[(long)id * 4 + 3] = b1;
    }
}

// ---------------------------------------------------------------------------
// LN2 stats from z (dense stride ZLD, cols 0..512 valid). One wave per row.
// st6[row*6] = { r1*r2, -r1*r2*mu2, r1, -r1*mu1, mu2*r2, r2 }
__global__ __launch_bounds__(256) void k_lnstats(
    const u16* __restrict__ z, const float* __restrict__ g2,
    const float* __restrict__ b2, float* __restrict__ st6)
{
    long row = (long)blockIdx.x * 4 + (threadIdx.x >> 6);
    int lane = threadIdx.x & 63;
    const u16* zp = z + row * ZLD;
    u16x8 z8 = *(const u16x8*)(zp + lane * 8);
    float S1 = 0.f, S2 = 0.f, Sg = 0.f, Sg2z2 = 0.f, Sg21 = 0.f, Sbg = 0.f;
    float cg = 0.f, cb = 0.f, cg2 = 0.f, cbg = 0.f, cb2 = 0.f;
#pragma unroll
    for (int j = 0; j < 8; j++) {
        int t = lane * 8 + j;
        float zv = bf2f(z8[j]);
        float g = g2[t], b = b2[t];
        S1 += zv; S2 += zv * zv;
        Sg += g * zv; Sg2z2 += g * g * zv * zv; Sg21 += g * g * zv;
        Sbg += g * b * zv;
        cg += g; cb += b; cg2 += g * g; cbg += g * b; cb2 += b * b;
    }
    if (lane == 0) {
        float zv = bf2f(zp[512]);
        float g = g2[512], b = b2[512];
        S1 += zv; S2 += zv * zv;
        Sg += g * zv; Sg2z2 += g * g * zv * zv; Sg21 += g * g * zv;
        Sbg += g * b * zv;
        cg += g; cb += b; cg2 += g * g; cbg += g * b; cb2 += b * b;
    }
    S1 = wredsum(S1); S2 = wredsum(S2); Sg = wredsum(Sg);
    Sg2z2 = wredsum(Sg2z2); Sg21 = wredsum(Sg21); Sbg = wredsum(Sbg);
    cg = wredsum(cg); cb = wredsum(cb); cg2 = wredsum(cg2);
    cbg = wredsum(cbg); cb2 = wredsum(cb2);
    if (lane == 0) {
        const float rT = 1.f / 513.f;
        float mu2 = S1 * rT;
        float var2 = S2 * rT - mu2 * mu2;
        float r2 = 1.f / sqrtf(var2 + 1e-5f);
        float mu1 = (r2 * (Sg - mu2 * cg) + cb) * rT;
        float Q2 = r2 * r2 * (Sg2z2 - 2.f * mu2 * Sg21 + mu2 * mu2 * cg2)
                 + 2.f * r2 * (Sbg - mu2 * cbg) + cb2;
        float var1 = Q2 * rT - mu1 * mu1;
        float r1 = 1.f / sqrtf(var1 + 1e-5f);
        float* o = st6 + row * 6;
        o[0] = r1 * r2;
        o[1] = -r1 * r2 * mu2;
        o[2] = r1;
        o[3] = -r1 * mu1;
        o[4] = mu2 * r2;
        o[5] = r2;
    }
}

// ---------------------------------------------------------------------------
// Fused qknorm + K-transpose + ksum. One block = 64 rows of one batch.
// qkv stride QKLD (Q at 0..511, K at 512..1023).
__global__ __launch_bounds__(256) void k_qkt(
    u16* __restrict__ qkv, u16* __restrict__ kpt,
    float* __restrict__ ksum, const float* __restrict__ scale, int l)
{
    long row0 = (long)blockIdx.x * 64;
    int b = (int)(row0 >> 11);
    int nloc = (int)(row0 & 2047);
    int tid = threadIdx.x, lane = tid & 63, w = tid >> 6;
    float s = log1pf(expf(scale[l]));
    __shared__ u16 Kp[64][520];
    __shared__ u16 T2[64 * 80];

#pragma unroll 4
    for (int i = 0; i < 16; i++) {
        int rl = w * 16 + i;
        u16* rp = qkv + (row0 + rl) * QKLD;
        u16x8 q8 = *(const u16x8*)(rp + lane * 8);
        u16x8 k8 = *(const u16x8*)(rp + 512 + lane * 8);
        float qf[8], kf[8];
        float sq = 0.f, sk = 0.f;
#pragma unroll
        for (int j = 0; j < 8; j++) { qf[j] = bf2f(q8[j]); sq += qf[j] * qf[j]; }
#pragma unroll
        for (int j = 0; j < 8; j++) { kf[j] = bf2f(k8[j]); sk += kf[j] * kf[j]; }
        sq = wredsum(sq); sk = wredsum(sk);
        float rnq = 1.f / fmaxf(sqrtf(sq), 1e-12f);
        float rnk = 1.f / fmaxf(sqrtf(sk), 1e-12f);
        u16x8 o, kk;
#pragma unroll
        for (int j = 0; j < 8; j++) {
            float q = qf[j] * rnq;
            float qp = (q > 0.f) ? (q + 1.f) : expf(q);
            o[j] = f2bf(qp * s);
            float kv = kf[j] * rnk;
            kv = (kv > 0.f) ? (kv + 1.f) : expf(kv);
            kk[j] = f2bf(kv);
        }
        *(u16x8*)(rp + lane * 8) = o;
        *(u16x8*)&Kp[rl][lane * 8] = kk;
    }
    __syncthreads();

    int r = tid >> 2;
    int c0 = (tid & 3) * 16;
    for (int ct = 0; ct < 8; ct++) {
        u16x8 a = *(const u16x8*)&Kp[r][ct * 64 + c0];
        u16x8 d = *(const u16x8*)&Kp[r][ct * 64 + c0 + 8];
#pragma unroll
        for (int j = 0; j < 8; j++) T2[(c0 + j) * 80 + r] = a[j];
#pragma unroll
        for (int j = 0; j < 8; j++) T2[(c0 + 8 + j) * 80 + r] = d[j];
        __syncthreads();
        u16x8 w0 = *(const u16x8*)&T2[r * 80 + c0];
        u16x8 w1 = *(const u16x8*)&T2[r * 80 + c0 + 8];
        u16* dst = kpt + ((long)(b * 512 + ct * 64 + r)) * 2048 + nloc + c0;
        *(u16x8*)dst = w0;
        *(u16x8*)(dst + 8) = w1;
        float part = 0.f;
#pragma unroll
        for (int j = 0; j < 8; j++) part += bf2f(w0[j]) + bf2f(w1[j]);
        part += __shfl_xor(part, 1, 64);
        part += __shfl_xor(part, 2, 64);
        if ((tid & 3) == 0)
            atomicAdd(&ksum[(long)b * 512 + ct * 64 + r], part);
        __syncthreads();
    }
}

// ---------------------------------------------------------------------------
__global__ __launch_bounds__(256) void k_denom(
    const u16* __restrict__ qkv, const float* __restrict__ ksum,
    float* __restrict__ denom)
{
    long row = (long)blockIdx.x * 4 + (threadIdx.x >> 6);
    int lane = threadIdx.x & 63;
    int b = (int)(row >> 11);
    u16x8 q = *(const u16x8*)(qkv + row * QKLD + lane * 8);
    const float* ks = ksum + (long)b * 512 + lane * 8;
    float acc = 0.f;
#pragma unroll
    for (int j = 0; j < 8; j++) acc += bf2f(q[j]) * ks[j];
    acc = wredsum(acc);
    if (lane == 0) denom[row] = acc;
}

// predict: on-the-fly LN2 of layer-3 z, then dot with pred_w.
__global__ void k_predict(const u16* __restrict__ z, const float* __restrict__ st6,
                          const float* __restrict__ g2, const float* __restrict__ b2,
                          const float* __restrict__ pw, float* __restrict__ out)
{
    int b = blockIdx.x;
    int lane = threadIdx.x;
    long row = (long)b * 2048 + 2047;
    const u16* rp = z + row * ZLD;
    float mu2r2 = st6[row * 6 + 4], r2 = st6[row * 6 + 5];
    float acc = 0.f;
    for (int t = lane; t < 513; t += 64) {
        float zt = bf2f(rp[t]);
        float tokv = zt * r2 * g2[t] - mu2r2 * g2[t] + b2[t];
        acc += tokv * pw[t];
    }
    acc = wredsum(acc);
    if (lane == 0) out[b] = acc;
}

// ---------------------------------------------------------------------------
// GEMM C[m][n] = sum_{k<K} A[m][k]*Bt[n][k]  (+ A[m][K]*Bt[n][K] if r1).
// 128x128 tile, BK=64, 4 waves, T2 LDS XOR-swizzle (both-sides).
// modes:
//  0: v = wv*cscale
//  1: v = wv*(cscale/(denom+eps)) + Res (direct bf16 add); aux1=denom
//  3: v = R1*(wv - R0*C2x) + C3x              [LN1 fold]
//  4: v = R0*wv + R1*C0x + R2*C1x + R3*C2x + C3x   [LN2.LN1 fold]
//  5: v = wv*R0 + ResLds*R2*C0 - R1*C0 + C1   [z + on-the-fly-LN2 residual]
// ldr = Res row stride; sRes = Res batch (bz) stride.
__global__ __launch_bounds__(256) void k_gemm_bt(
    const u16* __restrict__ A, const u16* __restrict__ Bt, u16* __restrict__ C,
    int M, int N, int K, int lda, int ldb, int ldc,
    long sA, long sB, long sC,
    const float* __restrict__ aux1, const float* __restrict__ aux2,
    const float* __restrict__ aux3, const float* __restrict__ aux4,
    long sAux, const u16* __restrict__ Res, int ldr, long sRes,
    float cscale, int mode, int r1, int padw,
    int ntm, int ntn, int nbz,
    u16* __restrict__ VT, int vtbase)
{
    int G = ntm * ntn * nbz;
    int id = blockIdx.x;
    int lin = (id & 7) * (G >> 3) + (id >> 3);
    int per = ntm * ntn;
    int bz = lin / per;
    int rem = lin - bz * per;
    int mt = rem / ntn;
    int nt = rem - mt * ntn;
    int m0 = mt * 128, n0 = nt * 128;

    A += (long)bz * sA; Bt += (long)bz * sB; C += (long)bz * sC;
    int tid = threadIdx.x, lane = tid & 63, w = tid >> 6;
    int wr = w >> 1, wc = w & 1;
    __shared__ u16 ldsbuf[2 * 128 * 64];      // Als | Bls; then Res/C tile
    u16* Als = ldsbuf;
    u16* Bls = ldsbuf + 128 * 64;
    __shared__ float auxR0[128], auxR1[128], auxR2[128], auxR3[128], auxA1[128];
    __shared__ float auxC0[128], auxC1[128], auxC2[128], auxC3[128], auxB1[128];

    if (tid < 128) {
        int gr = m0 + tid; if (gr >= M) gr = M - 1;
        float r0v = cscale, r1v = 0.f, r2v = 0.f, r3v = 0.f, a1v = 0.f;
        if (mode == 1 || mode == 5) {
            const float* d1 = aux1 + (long)bz * sAux;
            r0v = cscale / (d1[gr] + 1e-6f);
        }
        if (mode == 3) { r0v = aux1[gr]; r1v = aux2[gr]; }
        if (mode == 4) {
            r0v = aux1[(long)gr * 6 + 0]; r1v = aux1[(long)gr * 6 + 1];
            r2v = aux1[(long)gr * 6 + 2]; r3v = aux1[(long)gr * 6 + 3];
        }
        if (mode == 5) {
            long zr = (long)bz * 2048 + gr;
            r1v = aux2[zr * 6 + 4]; r2v = aux2[zr * 6 + 5];
        }
        if (r1) a1v = bf2f(A[(long)gr * lda + K]);
        auxR0[tid] = r0v; auxR1[tid] = r1v; auxR2[tid] = r2v; auxR3[tid] = r3v;
        auxA1[tid] = a1v;
    } else {
        int t = tid - 128;
        int gc = n0 + t; if (gc >= N) gc = N - 1;
        float c0v = 0.f, c1v = 0.f, c2v = 0.f, c3v = 0.f, b1v = 0.f;
        if (mode == 3) {
            c2v = aux3[(long)gc * 4 + 2]; c3v = aux3[(long)gc * 4 + 3];
        }
        if (mode == 4) {
            c0v = aux3[(long)gc * 4 + 0]; c1v = aux3[(long)gc * 4 + 1];
            c2v = aux3[(long)gc * 4 + 2]; c3v = aux3[(long)gc * 4 + 3];
        }
        if (mode == 5) {
            bool ok = gc < 513;
            c0v = ok ? aux3[gc] : 0.f;
            c1v = ok ? aux4[gc] : 0.f;
        }
        if (r1) b1v = bf2f(Bt[(long)gc * ldb + K]);
        auxC0[t] = c0v; auxC1[t] = c1v; auxC2[t] = c2v; auxC3[t] = c3v;
        auxB1[t] = b1v;
    }

    f32x4 acc[4][4];
#pragma unroll
    for (int m = 0; m < 4; m++)
#pragma unroll
        for (int n = 0; n < 4; n++) { acc[m][n][0]=0.f; acc[m][n][1]=0.f; acc[m][n][2]=0.f; acc[m][n][3]=0.f; }

    int srow = lane >> 3;
    int scol = (lane & 7) * 8;
    int scolsw = scol ^ (srow << 3);
    int swz = (lane & 7) << 3;

    for (int k0 = 0; k0 < K; k0 += 64) {
#pragma unroll
        for (int i = 0; i < 4; i++) {
            int rt = (w * 4 + i) * 8 + srow;
            int gr = m0 + rt; gr = (gr < M) ? gr : (M - 1);
            gload_lds16(A + (long)gr * lda + k0 + scolsw, &Als[(w * 4 + i) * 512]);
        }
#pragma unroll
        for (int i = 0; i < 4; i++) {
            int rt = (w * 4 + i) * 8 + srow;
            int gc = n0 + rt; gc = (gc < N) ? gc : (N - 1);
            gload_lds16(Bt + (long)gc * ldb + k0 + scolsw, &Bls[(w * 4 + i) * 512]);
        }
        __syncthreads();
#pragma unroll
        for (int ks = 0; ks < 2; ks++) {
            u16x8 af[4], bfv[4];
#pragma unroll
            for (int m = 0; m < 4; m++) {
                int row = wr * 64 + m * 16 + (lane & 15);
                af[m] = *(const u16x8*)&Als[row * 64 + ((ks * 32 + (lane >> 4) * 8) ^ swz)];
            }
#pragma unroll
            for (int n = 0; n < 4; n++) {
                int col = wc * 64 + n * 16 + (lane & 15);
                bfv[n] = *(const u16x8*)&Bls[col * 64 + ((ks * 32 + (lane >> 4) * 8) ^ swz)];
            }
#pragma unroll
            for (int m = 0; m < 4; m++)
#pragma unroll
                for (int n = 0; n < 4; n++)
                    acc[m][n] = mfma_16x16x32_bf16(af[m], bfv[n], acc[m][n]);
        }
        __syncthreads();
    }
    // LDS (Als/Bls) now dead; reuse for Res/C tile.

    bool isvt = (VT != nullptr) && (n0 >= vtbase);

    if (Res) {
        const u16* Rp = Res + (long)bz * sRes;
#pragma unroll
        for (int i = 0; i < 8; i++) {
            int lrow = i * 16 + (tid >> 4);
            int lcol = (tid & 15) * 8;
            long gr = m0 + lrow; if (gr > (long)M - 1) gr = M - 1;
            long gcol = (long)n0 + lcol;
            long mx = (long)N - 8; if (gcol > mx) gcol = mx;
            *(u16x8*)&ldsbuf[lrow * 128 + lcol] = *(const u16x8*)&Rp[gr * ldr + gcol];
        }
        __syncthreads();
    }

    asm volatile("s_nop 7\n\ts_nop 7" ::: );

    if (!isvt) {
        // normal pack: ldsbuf[row][col]
#pragma unroll
        for (int m = 0; m < 4; m++) {
            int lrbase = wr * 64 + m * 16 + ((lane >> 4) << 2);
#pragma unroll
            for (int n = 0; n < 4; n++) {
                int lc = wc * 64 + n * 16 + (lane & 15);
#pragma unroll
                for (int r = 0; r < 4; r++) {
                    int lr = lrbase + r;
                    float wv = acc[m][n][r] + auxA1[lr] * auxB1[lc];
                    float v;
                    if (mode == 3)
                        v = auxR1[lr] * (wv - auxR0[lr] * auxC2[lc]) + auxC3[lc];
                    else if (mode == 4)
                        v = auxR0[lr] * wv + auxR1[lr] * auxC0[lc]
                          + auxR2[lr] * auxC1[lc] + auxR3[lr] * auxC2[lc] + auxC3[lc];
                    else if (mode == 5)
                        v = wv * auxR0[lr]
                          + bf2f(ldsbuf[lr * 128 + lc]) * auxR2[lr] * auxC0[lc]
                          - auxR1[lr] * auxC0[lc] + auxC1[lc];
                    else {
                        v = wv * auxR0[lr];
                        if (Res) v += bf2f(ldsbuf[lr * 128 + lc]);
                    }
                    ldsbuf[lr * 128 + lc] = f2bf(v);
                }
            }
        }
        __syncthreads();

        int lcol = (tid & 15) * 8;
        int gc0 = n0 + lcol;
        bool colok = padw || (gc0 + 8 <= N);
#pragma unroll
        for (int i = 0; i < 8; i++) {
            int lrow = i * 16 + (tid >> 4);
            int gr = m0 + lrow;
            if (gr < M && colok) {
                *(u16x8*)&C[(long)gr * ldc + gc0] = *(const u16x8*)&ldsbuf[lrow * 128 + lcol];
            }
        }
    } else {
        // V-direct: pack transposed + XOR-swizzled: ldsbuf[u][token^((u&7)<<3)]
        int u0 = n0 - vtbase;
        int b = m0 >> 11;
        int nloc = m0 & 2047;
#pragma unroll
        for (int m = 0; m < 4; m++) {
            int lrbase = wr * 64 + m * 16 + ((lane >> 4) << 2);
#pragma unroll
            for (int n = 0; n < 4; n++) {
                int lc = wc * 64 + n * 16 + (lane & 15);
#pragma unroll
                for (int r = 0; r < 4; r++) {
                    int lr = lrbase + r;
                    float wv = acc[m][n][r] + auxA1[lr] * auxB1[lc];
                    float v;
                    if (mode == 3)
                        v = auxR1[lr] * (wv - auxR0[lr] * auxC2[lc]) + auxC3[lc];
                    else if (mode == 4)
                        v = auxR0[lr] * wv + auxR1[lr] * auxC0[lc]
                          + auxR2[lr] * auxC1[lc] + auxR3[lr] * auxC2[lc] + auxC3[lc];
                    else
                        v = wv * auxR0[lr];
                    ldsbuf[lc * 128 + (lr ^ ((lc & 7) << 3))] = f2bf(v);
                }
            }
        }
        __syncthreads();

        int nc = (tid & 15) * 8;          // token offset, 8-contiguous
        const u16x8 ones = {0x3F80,0x3F80,0x3F80,0x3F80,0x3F80,0x3F80,0x3F80,0x3F80};
#pragma unroll
        for (int i = 0; i < 8; i++) {
            int ur = i * 16 + (tid >> 4);
            int u = u0 + ur;
            if (u < VTROWS) {
                u16x8 vv;
                if (u == 513) vv = ones;
                else vv = *(const u16x8*)&ldsbuf[ur * 128 + (nc ^ ((ur & 7) << 3))];
                *(u16x8*)&VT[((long)b * VTROWS + u) * 2048 + nloc + nc] = vv;
            }
        }
    }
}

// ---------------------------------------------------------------------------
extern "C" void kernel_launch(void* const* d_in, const int* in_sizes, int n_in,
                              void* d_out, int out_size, void* d_ws, size_t ws_size,
                              hipStream_t stream)
{
    const float* xs    = (const float*)d_in[0];
    const float* ys    = (const float*)d_in[1];
    const float* qx    = (const float*)d_in[2];
    const float* Wq    = (const float*)d_in[3];
    const float* Wk    = (const float*)d_in[4];
    const float* Wv    = (const float*)d_in[5];
    const float* Wo    = (const float*)d_in[6];
    const float* ln1w  = (const float*)d_in[7];
    const float* ln1b  = (const float*)d_in[8];
    const float* ln2w  = (const float*)d_in[9];
    const float* ln2b  = (const float*)d_in[10];
    const float* scale = (const float*)d_in[11];
    const float* predw = (const float*)d_in[12];
    float* out = (float*)d_out;

    char* ws = (char*)d_ws;
    u16*   tok   = (u16*)(ws + 0L);              // 150,994,944
    u16*   buf1  = (u16*)(ws + 150994944L);      // vt (134.7 MB) + st6/xcol4 tail
    u16*   qkv   = (u16*)(ws + 301989888L);      // Q||K: 131072 x 1024 = 268.4 MB
    u16*   zbuf  = (u16*)(ws + 570425344L);      // z: 131072 x 576 = 151.0 MB
    u16*   kpt   = (u16*)(ws + 738197504L);      // 134,217,728  Kp^T / w2t
    u16*   kvh   = (u16*)(ws + 872415232L);      //  41,943,040
    float* denom = (float*)(ws + 914358272L);
    float* meanb = (float*)(ws + 914882560L);
    float* rstdb = (float*)(ws + 915406848L);
    float* ksum  = (float*)(ws + 915931136L);
    u16*   wcat  = (u16*)(ws + 916062208L);
    u16*   wop   = (u16*)(ws + 923729920L);
    float* st6   = (float*)(ws + 285736960L);    // buf1 tail: 131072*6*4 = 3.1MB
    float* xcol4 = (float*)(ws + 288882688L);    // buf1 tail: 4*1664*4*4
    u16*   w2t   = kpt;

    k_build_tokens<<<32768, 256, 0, stream>>>(xs, ys, qx, tok, meanb, rstdb);
    {
        long n1 = 4L * NQK * P;
        k_prep_wcat<<<(int)((n1 + 255) / 256), 256, 0, stream>>>(Wq, Wk, Wv, ln1w, ln2w, wcat);
        long n2 = 4L * P * P;
        k_prep_wo<<<(int)((n2 + 255) / 256), 256, 0, stream>>>(Wo, wop);
        k_prep_sums<<<1664, 256, 0, stream>>>(Wq, Wk, Wv, ln1w, ln1b, ln2w, ln2b, xcol4);
    }

    for (int l = 0; l < 4; l++) {
        hipMemsetAsync(ksum, 0, 64 * 512 * sizeof(float), stream);
        // QKV: K=512 + rank-1 (col 512); C=qkv (ldc=1024, Q||K); V tiles -> vt.
        // l==0: A=tok (mode 3, LN1 fold); l>=1: A=z_{l-1} dense (mode 4)
        if (l == 0) {
            k_gemm_bt<<<13312, 256, 0, stream>>>(tok, wcat, qkv,
                131072, NQK, 512, P, P, QKLD, 0, 0, 0,
                meanb, rstdb, xcol4, nullptr, 0, nullptr, 0, 0,
                1.f, 3, 1, 0, 1024, 13, 1,
                buf1, 1024);
        } else {
            k_gemm_bt<<<13312, 256, 0, stream>>>(zbuf, wcat + (long)l * NQK * P, qkv,
                131072, NQK, 512, ZLD, P, QKLD, 0, 0, 0,
                st6, nullptr, xcol4 + (long)l * NQK * 4, nullptr, 0, nullptr, 0, 0,
                1.f, 4, 1, 0, 1024, 13, 1,
                buf1, 1024);
        }
        // fused: Qp in place + Kp^T + ksum (atomics)
        k_qkt<<<2048, 256, 0, stream>>>(qkv, kpt, ksum, scale, l);
        // kvh[b][h][u] = sum_n Kp[n][h] V[n][u]
        k_gemm_bt<<<1280, 256, 0, stream>>>(kpt, buf1, kvh,
            512, VTROWS, 2048, 2048, 2048, KVLD,
            512L * 2048, (long)VTROWS * 2048, 512L * KVLD,
            nullptr, nullptr, nullptr, nullptr, 0, nullptr, 0, 0, 1.f, 0, 0, 1,
            4, 5, 64, nullptr, 1 << 30);
        k_denom<<<32768, 256, 0, stream>>>(qkv, ksum, denom);
        // w2t[b][t][h] = sum_{u<=512} Wo[t][u] kvh[b][h][u]  (K=512 + rank-1)
        k_gemm_bt<<<1280, 256, 0, stream>>>(wop + (long)l * P * P, kvh, w2t,
            576, 512, 512, P, KVLD, 512,
            0, 512L * KVLD, 576L * 512,
            nullptr, nullptr, nullptr, nullptr, 0, nullptr, 0, 0, 1.f, 0, 1, 0,
            5, 4, 64, nullptr, 1 << 30);
        // z_l = 0.1*(Qp @ w2t^T)/(denom+eps) + residual -> zbuf (dense 576).
        // l==0: Res=tok direct (mode 1); l>=1: Res=LN2(z_{l-1}) on the fly (mode 5)
        if (l == 0) {
            k_gemm_bt<<<5120, 256, 0, stream>>>(qkv, w2t, zbuf,
                2048, P, 512, QKLD, 512, ZLD,
                2048L * QKLD, 576L * 512, 2048L * ZLD,
                denom, nullptr, nullptr, nullptr, 2048, tok, P, 2048L * P,
                0.1f, 1, 0, 0, 16, 5, 64, nullptr, 1 << 30);
        } else {
            k_gemm_bt<<<5120, 256, 0, stream>>>(qkv, w2t, zbuf,
                2048, P, 512, QKLD, 512, ZLD,
                2048L * QKLD, 576L * 512, 2048L * ZLD,
                denom, st6, ln2w + (long)(l - 1) * 513, ln2b + (long)(l - 1) * 513,
                2048, zbuf, ZLD, 2048L * ZLD,
                0.1f, 5, 0, 0, 16, 5, 64, nullptr, 1 << 30);
        }
        // LN2 stats of z_l (for next QKV fold, next residual, and predict)
        k_lnstats<<<32768, 256, 0, stream>>>(zbuf, ln2w + (long)l * 513,
                                             ln2b + (long)l * 513, st6);
    }
    k_predict<<<64, 64, 0, stream>>>(zbuf, st6, ln2w + 3L * 513, ln2b + 3L * 513,
                                     predw, out);
}

// Round 10
// 3440.504 us; speedup vs baseline: 1.1458x; 1.1458x over previous
//
#include <hip/hip_runtime.h>
#include <cstdint>
#include <cstddef>

// ---------------------------------------------------------------------------
// MultiLayerAttentionModel on MI355X (gfx950), bf16 MFMA pipeline, round 17.
// REVERT to round-13 configuration (best verified: 3442 us). The LN2-fold
// arc (r14-r16) regressed ~500 us twice with two different z layouts —
// mode-4/5 epilogue + serial-chain cost exceeds the k_ln2 savings. r13:
// K=512+rank-1 QKV (LN1 fold, mode 3), T2 swizzle, fused k_qkt (qknorm +
// K-transpose + ksum atomics), k_ln2 materializes tok per layer.
// ---------------------------------------------------------------------------

typedef unsigned short u16;
typedef float f32x4 __attribute__((ext_vector_type(4)));
typedef unsigned short u16x8 __attribute__((ext_vector_type(8)));

#define P 576
#define NQK 1664
#define VTROWS 514
#define KVLD 640

__device__ __forceinline__ float bf2f(u16 s) {
    union { unsigned u; float f; } v; v.u = ((unsigned)s) << 16; return v.f;
}
__device__ __forceinline__ u16 f2bf(float f) {
    union { float f; unsigned u; } v; v.f = f;
    unsigned r = v.u + 0x7FFF + ((v.u >> 16) & 1);
    return (u16)(r >> 16);
}
__device__ __forceinline__ float wredsum(float v) {
#pragma unroll
    for (int o = 32; o > 0; o >>= 1) v += __shfl_xor(v, o, 64);
    return v;
}
__device__ __forceinline__ f32x4 mfma_16x16x32_bf16(u16x8 a, u16x8 b, f32x4 c) {
    asm volatile("v_mfma_f32_16x16x32_bf16 %0, %1, %2, %0"
                 : "+v"(c) : "v"(a), "v"(b));
    return c;
}
__device__ __forceinline__ void gload_lds16(const u16* g, u16* l) {
    __builtin_amdgcn_global_load_lds(
        (const __attribute__((address_space(1))) void*)g,
        (__attribute__((address_space(3))) void*)l, 16, 0, 0);
}

// ---------------------------------------------------------------------------
__global__ __launch_bounds__(256) void k_build_tokens(
    const float* __restrict__ xs, const float* __restrict__ ys,
    const float* __restrict__ qx, u16* __restrict__ tok,
    float* __restrict__ meanb, float* __restrict__ rstdb)
{
    long row = (long)blockIdx.x * 4 + (threadIdx.x >> 6);
    int lane = threadIdx.x & 63;
    int b = (int)(row >> 11), n = (int)(row & 2047);
    const float* src = (n < 2047) ? xs + ((long)(b * 2047 + n)) * 512
                                  : qx + (long)b * 512;
    float4 f0 = *(const float4*)(src + lane * 8);
    float4 f1 = *(const float4*)(src + lane * 8 + 4);
    float y = (n < 2047) ? ys[(long)b * 2047 + n] : 0.f;
    float v[8] = {f0.x, f0.y, f0.z, f0.w, f1.x, f1.y, f1.z, f1.w};
    float s = 0.f, sq = 0.f;
#pragma unroll
    for (int j = 0; j < 8; j++) { s += v[j]; sq += v[j] * v[j]; }
    if (lane == 0) { s += y; sq += y * y; }
    s = wredsum(s); sq = wredsum(sq);
    u16x8 o;
#pragma unroll
    for (int j = 0; j < 8; j++) o[j] = f2bf(v[j]);
    *(u16x8*)(tok + row * P + lane * 8) = o;
    if (lane < 8) {
        u16x8 z8 = {0,0,0,0,0,0,0,0};
        if (lane == 0) z8[0] = f2bf(y);
        *(u16x8*)(tok + row * P + 512 + lane * 8) = z8;
    }
    if (lane == 0) {
        float m = s * (1.f / 513.f);
        float var = sq * (1.f / 513.f) - m * m;
        meanb[row] = m;
        rstdb[row] = 1.f / sqrtf(var + 1e-5f);
    }
}

__global__ __launch_bounds__(256) void k_prep_wcat(
    const float* __restrict__ wq, const float* __restrict__ wk,
    const float* __restrict__ wv, const float* __restrict__ ln1w,
    u16* __restrict__ wcat)
{
    long idx = (long)blockIdx.x * 256 + threadIdx.x;
    if (idx >= 4L * NQK * P) return;
    int t = (int)(idx % P);
    long rem = idx / P;
    int r = (int)(rem % NQK);
    int l = (int)(rem / NQK);
    float v = 0.f;
    if (t < 513) {
        float wsc = ln1w[l * 513 + t];
        if (r < 512)       v = wq[((long)l * 512 + r) * 513 + t] * wsc;
        else if (r < 1024) v = wk[((long)l * 512 + (r - 512)) * 513 + t] * wsc;
        else if (r < 1537) v = wv[((long)l * 513 + (r - 1024)) * 513 + t] * wsc;
    }
    wcat[idx] = f2bf(v);
}

__global__ __launch_bounds__(256) void k_prep_wo(
    const float* __restrict__ wo, u16* __restrict__ wop)
{
    long idx = (long)blockIdx.x * 256 + threadIdx.x;
    if (idx >= 4L * P * P) return;
    int u = (int)(idx % P);
    long rem = idx / P;
    int t = (int)(rem % P);
    int l = (int)(rem / P);
    float v = (t < 513 && u < 513) ? wo[((long)l * 513 + t) * 513 + u] : 0.f;
    wop[idx] = f2bf(v);
}

__global__ __launch_bounds__(256) void k_prep_sums(
    const float* __restrict__ wq, const float* __restrict__ wk,
    const float* __restrict__ wv, const float* __restrict__ ln1w,
    const float* __restrict__ ln1b, float* __restrict__ s1, float* __restrict__ s2)
{
    int id = blockIdx.x * 4 + (threadIdx.x >> 6);
    int lane = threadIdx.x & 63;
    int l = id / NQK, r = id % NQK;
    float a1 = 0.f, a2 = 0.f;
    for (int t = lane; t < 513; t += 64) {
        float wc = 0.f;
        if (r < 512)       wc = wq[((long)l * 512 + r) * 513 + t];
        else if (r < 1024) wc = wk[((long)l * 512 + (r - 512)) * 513 + t];
        else if (r < 1537) wc = wv[((long)l * 513 + (r - 1024)) * 513 + t];
        a1 += ln1w[l * 513 + t] * wc;
        a2 += ln1b[l * 513 + t] * wc;
    }
    a1 = wredsum(a1); a2 = wredsum(a2);
    if (lane == 0) { s1[id] = a1; s2[id] = a2; }
}

// ---------------------------------------------------------------------------
__global__ __launch_bounds__(256) void k_ln2(
    const u16* __restrict__ z, u16* __restrict__ tok,
    const float* __restrict__ w, const float* __restrict__ bia,
    float* __restrict__ meanb, float* __restrict__ rstdb)
{
    long row = (long)blockIdx.x * 4 + (threadIdx.x >> 6);
    int lane = threadIdx.x & 63;
    const u16* zp = z + row * P;
    u16* tp = tok + row * P;
    u16x8 a0 = *(const u16x8*)(zp + lane * 8);
    u16x8 a1 = {0,0,0,0,0,0,0,0};
    if (lane < 8) a1 = *(const u16x8*)(zp + 512 + lane * 8);
    float v0[8], v1[8];
#pragma unroll
    for (int j = 0; j < 8; j++) v0[j] = bf2f(a0[j]);
#pragma unroll
    for (int j = 0; j < 8; j++) v1[j] = (lane < 8) ? bf2f(a1[j]) : 0.f;
    float s = 0.f, sq = 0.f;
#pragma unroll
    for (int j = 0; j < 8; j++) { s += v0[j]; sq += v0[j] * v0[j]; }
#pragma unroll
    for (int j = 0; j < 8; j++) { s += v1[j]; sq += v1[j] * v1[j]; }
    s = wredsum(s); sq = wredsum(sq);
    float mean = s * (1.f / 513.f);
    float var = sq * (1.f / 513.f) - mean * mean;
    float rstd = 1.f / sqrtf(var + 1e-5f);
    float so = 0.f, so2 = 0.f;
    u16x8 o0;
    float of0[8];
#pragma unroll
    for (int j = 0; j < 8; j++) {
        int t = lane * 8 + j;
        of0[j] = (v0[j] - mean) * rstd * w[t] + bia[t];
        so += of0[j]; so2 += of0[j] * of0[j];
        o0[j] = f2bf(of0[j]);
    }
    float of1[8];
#pragma unroll
    for (int j = 0; j < 8; j++) {
        int t = 512 + lane * 8 + j;
        float ov = 0.f;
        if (lane < 8 && t < 513) ov = (v1[j] - mean) * rstd * w[t] + bia[t];
        of1[j] = ov;
        so += ov; so2 += ov * ov;
    }
    so = wredsum(so); so2 = wredsum(so2);
    *(u16x8*)(tp + lane * 8) = o0;
    if (lane < 8) {
        u16x8 o1;
#pragma unroll
        for (int j = 0; j < 8; j++) o1[j] = f2bf(of1[j]);
        *(u16x8*)(tp + 512 + lane * 8) = o1;
    }
    if (lane == 0) {
        float m2 = so * (1.f / 513.f);
        float v2 = so2 * (1.f / 513.f) - m2 * m2;
        meanb[row] = m2;
        rstdb[row] = 1.f / sqrtf(v2 + 1e-5f);
    }
}

// ---------------------------------------------------------------------------
// Fused qknorm + K-transpose + ksum. One block = 64 rows of one batch.
__global__ __launch_bounds__(256) void k_qkt(
    u16* __restrict__ qkv, u16* __restrict__ kpt,
    float* __restrict__ ksum, const float* __restrict__ scale, int l)
{
    long row0 = (long)blockIdx.x * 64;
    int b = (int)(row0 >> 11);
    int nloc = (int)(row0 & 2047);
    int tid = threadIdx.x, lane = tid & 63, w = tid >> 6;
    float s = log1pf(expf(scale[l]));
    __shared__ u16 Kp[64][520];
    __shared__ u16 T2[64 * 80];

#pragma unroll 4
    for (int i = 0; i < 16; i++) {
        int rl = w * 16 + i;
        u16* rp = qkv + (row0 + rl) * NQK;
        u16x8 q8 = *(const u16x8*)(rp + lane * 8);
        u16x8 k8 = *(const u16x8*)(rp + 512 + lane * 8);
        float qf[8], kf[8];
        float sq = 0.f, sk = 0.f;
#pragma unroll
        for (int j = 0; j < 8; j++) { qf[j] = bf2f(q8[j]); sq += qf[j] * qf[j]; }
#pragma unroll
        for (int j = 0; j < 8; j++) { kf[j] = bf2f(k8[j]); sk += kf[j] * kf[j]; }
        sq = wredsum(sq); sk = wredsum(sk);
        float rnq = 1.f / fmaxf(sqrtf(sq), 1e-12f);
        float rnk = 1.f / fmaxf(sqrtf(sk), 1e-12f);
        u16x8 o, kk;
#pragma unroll
        for (int j = 0; j < 8; j++) {
            float q = qf[j] * rnq;
            float qp = (q > 0.f) ? (q + 1.f) : expf(q);
            o[j] = f2bf(qp * s);
            float kv = kf[j] * rnk;
            kv = (kv > 0.f) ? (kv + 1.f) : expf(kv);
            kk[j] = f2bf(kv);
        }
        *(u16x8*)(rp + lane * 8) = o;
        *(u16x8*)&Kp[rl][lane * 8] = kk;
    }
    __syncthreads();

    int r = tid >> 2;
    int c0 = (tid & 3) * 16;
    for (int ct = 0; ct < 8; ct++) {
        u16x8 a = *(const u16x8*)&Kp[r][ct * 64 + c0];
        u16x8 d = *(const u16x8*)&Kp[r][ct * 64 + c0 + 8];
#pragma unroll
        for (int j = 0; j < 8; j++) T2[(c0 + j) * 80 + r] = a[j];
#pragma unroll
        for (int j = 0; j < 8; j++) T2[(c0 + 8 + j) * 80 + r] = d[j];
        __syncthreads();
        u16x8 w0 = *(const u16x8*)&T2[r * 80 + c0];
        u16x8 w1 = *(const u16x8*)&T2[r * 80 + c0 + 8];
        u16* dst = kpt + ((long)(b * 512 + ct * 64 + r)) * 2048 + nloc + c0;
        *(u16x8*)dst = w0;
        *(u16x8*)(dst + 8) = w1;
        float part = 0.f;
#pragma unroll
        for (int j = 0; j < 8; j++) part += bf2f(w0[j]) + bf2f(w1[j]);
        part += __shfl_xor(part, 1, 64);
        part += __shfl_xor(part, 2, 64);
        if ((tid & 3) == 0)
            atomicAdd(&ksum[(long)b * 512 + ct * 64 + r], part);
        __syncthreads();
    }
}

// ---------------------------------------------------------------------------
__global__ __launch_bounds__(256) void k_denom(
    const u16* __restrict__ qkv, const float* __restrict__ ksum,
    float* __restrict__ denom)
{
    long row = (long)blockIdx.x * 4 + (threadIdx.x >> 6);
    int lane = threadIdx.x & 63;
    int b = (int)(row >> 11);
    u16x8 q = *(const u16x8*)(qkv + row * NQK + lane * 8);
    const float* ks = ksum + (long)b * 512 + lane * 8;
    float acc = 0.f;
#pragma unroll
    for (int j = 0; j < 8; j++) acc += bf2f(q[j]) * ks[j];
    acc = wredsum(acc);
    if (lane == 0) denom[row] = acc;
}

__global__ void k_predict(const u16* __restrict__ tok, const float* __restrict__ pw,
                          float* __restrict__ out)
{
    int b = blockIdx.x;
    int lane = threadIdx.x;
    const u16* rp = tok + ((long)b * 2048 + 2047) * P;
    float acc = 0.f;
    for (int t = lane; t < 513; t += 64) acc += bf2f(rp[t]) * pw[t];
    acc = wredsum(acc);
    if (lane == 0) out[b] = acc;
}

// ---------------------------------------------------------------------------
// GEMM C[m][n] = sum_{k<K} A[m][k]*Bt[n][k]  (+ A[m][K]*Bt[n][K] if r1).
// 128x128 tile, BK=64, 4 waves. 1-D grid, bijective XCD-chunked swizzle.
// T2 LDS XOR-swizzle (both-sides): pre-swizzled global source column for
// global_load_lds + matching XOR on ds_read_b128 fragment reads.
__global__ __launch_bounds__(256) void k_gemm_bt(
    const u16* __restrict__ A, const u16* __restrict__ Bt, u16* __restrict__ C,
    int M, int N, int K, int lda, int ldb, int ldc,
    long sA, long sB, long sC,
    const float* __restrict__ aux1, const float* __restrict__ aux2,
    const float* __restrict__ aux3, const float* __restrict__ aux4,
    long sAux, const u16* __restrict__ Res,
    float cscale, int mode, int r1, int padw,
    int ntm, int ntn, int nbz,
    u16* __restrict__ VT, int vtbase)
{
    int G = ntm * ntn * nbz;
    int id = blockIdx.x;
    int lin = (id & 7) * (G >> 3) + (id >> 3);
    int per = ntm * ntn;
    int bz = lin / per;
    int rem = lin - bz * per;
    int mt = rem / ntn;
    int nt = rem - mt * ntn;
    int m0 = mt * 128, n0 = nt * 128;

    A += (long)bz * sA; Bt += (long)bz * sB; C += (long)bz * sC;
    int tid = threadIdx.x, lane = tid & 63, w = tid >> 6;
    int wr = w >> 1, wc = w & 1;
    __shared__ u16 ldsbuf[2 * 128 * 64];      // Als | Bls; then Res/C tile
    u16* Als = ldsbuf;
    u16* Bls = ldsbuf + 128 * 64;
    __shared__ float auxR0[128], auxR1[128], auxA1[128];
    __shared__ float auxC0[128], auxC1[128], auxB1[128];

    if (tid < 128) {
        int gr = m0 + tid; if (gr >= M) gr = M - 1;
        float r0v = cscale, r1v = 0.f, a1v = 0.f;
        if (mode == 1) {
            const float* d1 = aux1 + (long)bz * sAux;
            r0v = cscale / (d1[gr] + 1e-6f);
        } else if (mode == 3) { r0v = aux1[gr]; r1v = aux2[gr]; }
        if (r1) a1v = bf2f(A[(long)gr * lda + K]);
        auxR0[tid] = r0v; auxR1[tid] = r1v; auxA1[tid] = a1v;
    } else {
        int t = tid - 128;
        int gc = n0 + t; if (gc >= N) gc = N - 1;
        float c0v = 0.f, c1v = 0.f, b1v = 0.f;
        if (mode == 3) { c0v = aux3[gc]; c1v = aux4[gc]; }
        if (r1) b1v = bf2f(Bt[(long)gc * ldb + K]);
        auxC0[t] = c0v; auxC1[t] = c1v; auxB1[t] = b1v;
    }

    f32x4 acc[4][4];
#pragma unroll
    for (int m = 0; m < 4; m++)
#pragma unroll
        for (int n = 0; n < 4; n++) { acc[m][n][0]=0.f; acc[m][n][1]=0.f; acc[m][n][2]=0.f; acc[m][n][3]=0.f; }

    int srow = lane >> 3;
    int scol = (lane & 7) * 8;
    int scolsw = scol ^ (srow << 3);
    int swz = (lane & 7) << 3;

    for (int k0 = 0; k0 < K; k0 += 64) {
#pragma unroll
        for (int i = 0; i < 4; i++) {
            int rt = (w * 4 + i) * 8 + srow;
            int gr = m0 + rt; gr = (gr < M) ? gr : (M - 1);
            gload_lds16(A + (long)gr * lda + k0 + scolsw, &Als[(w * 4 + i) * 512]);
        }
#pragma unroll
        for (int i = 0; i < 4; i++) {
            int rt = (w * 4 + i) * 8 + srow;
            int gc = n0 + rt; gc = (gc < N) ? gc : (N - 1);
            gload_lds16(Bt + (long)gc * ldb + k0 + scolsw, &Bls[(w * 4 + i) * 512]);
        }
        __syncthreads();
#pragma unroll
        for (int ks = 0; ks < 2; ks++) {
            u16x8 af[4], bfv[4];
#pragma unroll
            for (int m = 0; m < 4; m++) {
                int row = wr * 64 + m * 16 + (lane & 15);
                af[m] = *(const u16x8*)&Als[row * 64 + ((ks * 32 + (lane >> 4) * 8) ^ swz)];
            }
#pragma unroll
            for (int n = 0; n < 4; n++) {
                int col = wc * 64 + n * 16 + (lane & 15);
                bfv[n] = *(const u16x8*)&Bls[col * 64 + ((ks * 32 + (lane >> 4) * 8) ^ swz)];
            }
#pragma unroll
            for (int m = 0; m < 4; m++)
#pragma unroll
                for (int n = 0; n < 4; n++)
                    acc[m][n] = mfma_16x16x32_bf16(af[m], bfv[n], acc[m][n]);
        }
        __syncthreads();
    }
    // LDS (Als/Bls) now dead; reuse for Res/C tile.

    bool isvt = (VT != nullptr) && (n0 >= vtbase);

    if (Res) {
        const u16* Rp = Res + (long)bz * sC;
#pragma unroll
        for (int i = 0; i < 8; i++) {
            int lrow = i * 16 + (tid >> 4);
            int lcol = (tid & 15) * 8;
            long gr = m0 + lrow; if (gr > (long)M - 1) gr = M - 1;
            long gcol = (long)n0 + lcol;
            long mx = (long)ldc - 8; if (gcol > mx) gcol = mx;
            *(u16x8*)&ldsbuf[lrow * 128 + lcol] = *(const u16x8*)&Rp[gr * ldc + gcol];
        }
        __syncthreads();
    }

    asm volatile("s_nop 7\n\ts_nop 7" ::: );

    if (!isvt) {
        // normal pack: ldsbuf[row][col]
#pragma unroll
        for (int m = 0; m < 4; m++) {
            int lrbase = wr * 64 + m * 16 + ((lane >> 4) << 2);
#pragma unroll
            for (int n = 0; n < 4; n++) {
                int lc = wc * 64 + n * 16 + (lane & 15);
                float c0v = auxC0[lc], c1v = auxC1[lc], b1v = auxB1[lc];
#pragma unroll
                for (int r = 0; r < 4; r++) {
                    int lr = lrbase + r;
                    float wv = acc[m][n][r] + auxA1[lr] * b1v;
                    float v;
                    if (mode == 3) v = auxR1[lr] * (wv - auxR0[lr] * c0v) + c1v;
                    else {
                        v = wv * auxR0[lr];
                        if (Res) v += bf2f(ldsbuf[lr * 128 + lc]);
                    }
                    ldsbuf[lr * 128 + lc] = f2bf(v);
                }
            }
        }
        __syncthreads();

        int lcol = (tid & 15) * 8;
        int gc0 = n0 + lcol;
        bool colok = padw || (gc0 + 8 <= N);
#pragma unroll
        for (int i = 0; i < 8; i++) {
            int lrow = i * 16 + (tid >> 4);
            int gr = m0 + lrow;
            if (gr < M && colok) {
                *(u16x8*)&C[(long)gr * ldc + gc0] = *(const u16x8*)&ldsbuf[lrow * 128 + lcol];
            }
        }
    } else {
        // V-direct: pack transposed + XOR-swizzled: ldsbuf[u][token^((u&7)<<3)]
        // (includes rank-1 term when r1 — required for K=512+r1 QKV)
        int u0 = n0 - vtbase;
        int b = m0 >> 11;
        int nloc = m0 & 2047;
#pragma unroll
        for (int m = 0; m < 4; m++) {
            int lrbase = wr * 64 + m * 16 + ((lane >> 4) << 2);
#pragma unroll
            for (int n = 0; n < 4; n++) {
                int lc = wc * 64 + n * 16 + (lane & 15);
                float c0v = auxC0[lc], c1v = auxC1[lc], b1v = auxB1[lc];
#pragma unroll
                for (int r = 0; r < 4; r++) {
                    int lr = lrbase + r;
                    float wv = acc[m][n][r] + auxA1[lr] * b1v;
                    float v = (mode == 3) ? (auxR1[lr] * (wv - auxR0[lr] * c0v) + c1v)
                                          : (wv * auxR0[lr]);
                    ldsbuf[lc * 128 + (lr ^ ((lc & 7) << 3))] = f2bf(v);
                }
            }
        }
        __syncthreads();

        int nc = (tid & 15) * 8;          // token offset, 8-contiguous
        const u16x8 ones = {0x3F80,0x3F80,0x3F80,0x3F80,0x3F80,0x3F80,0x3F80,0x3F80};
#pragma unroll
        for (int i = 0; i < 8; i++) {
            int ur = i * 16 + (tid >> 4);
            int u = u0 + ur;
            if (u < VTROWS) {
                u16x8 vv;
                if (u == 513) vv = ones;
                else vv = *(const u16x8*)&ldsbuf[ur * 128 + (nc ^ ((ur & 7) << 3))];
                *(u16x8*)&VT[((long)b * VTROWS + u) * 2048 + nloc + nc] = vv;
            }
        }
    }
}

// ---------------------------------------------------------------------------
extern "C" void kernel_launch(void* const* d_in, const int* in_sizes, int n_in,
                              void* d_out, int out_size, void* d_ws, size_t ws_size,
                              hipStream_t stream)
{
    const float* xs    = (const float*)d_in[0];
    const float* ys    = (const float*)d_in[1];
    const float* qx    = (const float*)d_in[2];
    const float* Wq    = (const float*)d_in[3];
    const float* Wk    = (const float*)d_in[4];
    const float* Wv    = (const float*)d_in[5];
    const float* Wo    = (const float*)d_in[6];
    const float* ln1w  = (const float*)d_in[7];
    const float* ln1b  = (const float*)d_in[8];
    const float* ln2w  = (const float*)d_in[9];
    const float* ln2b  = (const float*)d_in[10];
    const float* scale = (const float*)d_in[11];
    const float* predw = (const float*)d_in[12];
    float* out = (float*)d_out;

    char* ws = (char*)d_ws;
    u16*   tok   = (u16*)(ws + 0L);              // 150,994,944
    u16*   buf1  = (u16*)(ws + 150994944L);      // 150,994,944  vt then z
    u16*   qkv   = (u16*)(ws + 301989888L);      // 436,207,616
    u16*   kpt   = (u16*)(ws + 738197504L);      // 134,217,728  Kp^T / w2t
    u16*   kvh   = (u16*)(ws + 872415232L);      //  41,943,040
    float* denom = (float*)(ws + 914358272L);
    float* meanb = (float*)(ws + 914882560L);
    float* rstdb = (float*)(ws + 915406848L);
    float* ksum  = (float*)(ws + 915931136L);
    u16*   wcat  = (u16*)(ws + 916062208L);
    u16*   wop   = (u16*)(ws + 923729920L);
    float* s1    = (float*)(ws + 926384128L);
    float* s2    = (float*)(ws + 926410752L);
    u16*   w2t   = kpt;

    k_build_tokens<<<32768, 256, 0, stream>>>(xs, ys, qx, tok, meanb, rstdb);
    {
        long n1 = 4L * NQK * P;
        k_prep_wcat<<<(int)((n1 + 255) / 256), 256, 0, stream>>>(Wq, Wk, Wv, ln1w, wcat);
        long n2 = 4L * P * P;
        k_prep_wo<<<(int)((n2 + 255) / 256), 256, 0, stream>>>(Wo, wop);
        k_prep_sums<<<1664, 256, 0, stream>>>(Wq, Wk, Wv, ln1w, ln1b, s1, s2);
    }

    for (int l = 0; l < 4; l++) {
        hipMemsetAsync(ksum, 0, 64 * 512 * sizeof(float), stream);
        // QKV = LN-folded GEMM; K=512 + rank-1 (col 512); V tiles -> vt
        k_gemm_bt<<<13312, 256, 0, stream>>>(tok, wcat + (long)l * NQK * P, qkv,
            131072, NQK, 512, P, P, NQK, 0, 0, 0,
            meanb, rstdb, s1 + l * NQK, s2 + l * NQK, 0, nullptr,
            1.f, 3, 1, 0, 1024, 13, 1,
            buf1, 1024);
        // fused: Qp in place + Kp^T + ksum (atomics)
        k_qkt<<<2048, 256, 0, stream>>>(qkv, kpt, ksum, scale, l);
        // kvh[b][h][u] = sum_n Kp[n][h] V[n][u]
        k_gemm_bt<<<1280, 256, 0, stream>>>(kpt, buf1, kvh,
            512, VTROWS, 2048, 2048, 2048, KVLD,
            512L * 2048, (long)VTROWS * 2048, 512L * KVLD,
            nullptr, nullptr, nullptr, nullptr, 0, nullptr, 1.f, 0, 0, 1,
            4, 5, 64, nullptr, 1 << 30);
        k_denom<<<32768, 256, 0, stream>>>(qkv, ksum, denom);
        // w2t[b][t][h] = sum_{u<=512} Wo[t][u] kvh[b][h][u]  (K=512 + rank-1)
        k_gemm_bt<<<1280, 256, 0, stream>>>(wop + (long)l * P * P, kvh, w2t,
            576, 512, 512, P, KVLD, 512,
            0, 512L * KVLD, 576L * 512,
            nullptr, nullptr, nullptr, nullptr, 0, nullptr, 1.f, 0, 1, 0,
            5, 4, 64, nullptr, 1 << 30);
        // z = 0.1*(Qp @ w2t^T)/(denom+eps) + tok
        k_gemm_bt<<<5120, 256, 0, stream>>>(qkv, w2t, buf1,
            2048, P, 512, NQK, 512, P,
            2048L * NQK, 576L * 512, 2048L * P,
            denom, nullptr, nullptr, nullptr, 2048, tok,
            0.1f, 1, 0, 0, 16, 5, 64, nullptr, 1 << 30);
        // tok = LN2(z) + next-layer stats
        k_ln2<<<32768, 256, 0, stream>>>(buf1, tok, ln2w + l * 513, ln2b + l * 513,
                                         meanb, rstdb);
    }
    k_predict<<<64, 64, 0, stream>>>(tok, predw, out);
}

// Round 11
// 3340.634 us; speedup vs baseline: 1.1801x; 1.0299x over previous
//
#include <hip/hip_runtime.h>
#include <cstdint>
#include <cstddef>

// ---------------------------------------------------------------------------
// MultiLayerAttentionModel on MI355X (gfx950), bf16 MFMA pipeline, round 18.
// Round 17 (= r13 best, 3440us) + N-pad removal on the two mid GEMMs:
//  - kvh GEMM N 514->512 (4 clean tiles): col 513 (Ksum) was already dead;
//    col 512 = Kp^T . V[:,512] now computed in k_qkt (matvec vs vt row 512,
//    f32 atomics) + k_v512 converts into kvh col 512 for w2t's rank-1.
//  - z GEMM N 576->512 (4 clean tiles): col-512 numerator folded into
//    k_denom as a second dot (Qp . w2t[b][512][:]) -> znum512; k_ln2
//    synthesizes z col 512 = 0.1*znum/(denom+eps) + tok[512] in f32.
// k_denom moved after the w2t GEMM (needs w2t row 512). GEMM core untouched.
// ---------------------------------------------------------------------------

typedef unsigned short u16;
typedef float f32x4 __attribute__((ext_vector_type(4)));
typedef unsigned short u16x8 __attribute__((ext_vector_type(8)));

#define P 576
#define NQK 1664
#define VTROWS 514
#define KVLD 640

__device__ __forceinline__ float bf2f(u16 s) {
    union { unsigned u; float f; } v; v.u = ((unsigned)s) << 16; return v.f;
}
__device__ __forceinline__ u16 f2bf(float f) {
    union { float f; unsigned u; } v; v.f = f;
    unsigned r = v.u + 0x7FFF + ((v.u >> 16) & 1);
    return (u16)(r >> 16);
}
__device__ __forceinline__ float wredsum(float v) {
#pragma unroll
    for (int o = 32; o > 0; o >>= 1) v += __shfl_xor(v, o, 64);
    return v;
}
__device__ __forceinline__ f32x4 mfma_16x16x32_bf16(u16x8 a, u16x8 b, f32x4 c) {
    asm volatile("v_mfma_f32_16x16x32_bf16 %0, %1, %2, %0"
                 : "+v"(c) : "v"(a), "v"(b));
    return c;
}
__device__ __forceinline__ void gload_lds16(const u16* g, u16* l) {
    __builtin_amdgcn_global_load_lds(
        (const __attribute__((address_space(1))) void*)g,
        (__attribute__((address_space(3))) void*)l, 16, 0, 0);
}

// ---------------------------------------------------------------------------
__global__ __launch_bounds__(256) void k_build_tokens(
    const float* __restrict__ xs, const float* __restrict__ ys,
    const float* __restrict__ qx, u16* __restrict__ tok,
    float* __restrict__ meanb, float* __restrict__ rstdb)
{
    long row = (long)blockIdx.x * 4 + (threadIdx.x >> 6);
    int lane = threadIdx.x & 63;
    int b = (int)(row >> 11), n = (int)(row & 2047);
    const float* src = (n < 2047) ? xs + ((long)(b * 2047 + n)) * 512
                                  : qx + (long)b * 512;
    float4 f0 = *(const float4*)(src + lane * 8);
    float4 f1 = *(const float4*)(src + lane * 8 + 4);
    float y = (n < 2047) ? ys[(long)b * 2047 + n] : 0.f;
    float v[8] = {f0.x, f0.y, f0.z, f0.w, f1.x, f1.y, f1.z, f1.w};
    float s = 0.f, sq = 0.f;
#pragma unroll
    for (int j = 0; j < 8; j++) { s += v[j]; sq += v[j] * v[j]; }
    if (lane == 0) { s += y; sq += y * y; }
    s = wredsum(s); sq = wredsum(sq);
    u16x8 o;
#pragma unroll
    for (int j = 0; j < 8; j++) o[j] = f2bf(v[j]);
    *(u16x8*)(tok + row * P + lane * 8) = o;
    if (lane < 8) {
        u16x8 z8 = {0,0,0,0,0,0,0,0};
        if (lane == 0) z8[0] = f2bf(y);
        *(u16x8*)(tok + row * P + 512 + lane * 8) = z8;
    }
    if (lane == 0) {
        float m = s * (1.f / 513.f);
        float var = sq * (1.f / 513.f) - m * m;
        meanb[row] = m;
        rstdb[row] = 1.f / sqrtf(var + 1e-5f);
    }
}

__global__ __launch_bounds__(256) void k_prep_wcat(
    const float* __restrict__ wq, const float* __restrict__ wk,
    const float* __restrict__ wv, const float* __restrict__ ln1w,
    u16* __restrict__ wcat)
{
    long idx = (long)blockIdx.x * 256 + threadIdx.x;
    if (idx >= 4L * NQK * P) return;
    int t = (int)(idx % P);
    long rem = idx / P;
    int r = (int)(rem % NQK);
    int l = (int)(rem / NQK);
    float v = 0.f;
    if (t < 513) {
        float wsc = ln1w[l * 513 + t];
        if (r < 512)       v = wq[((long)l * 512 + r) * 513 + t] * wsc;
        else if (r < 1024) v = wk[((long)l * 512 + (r - 512)) * 513 + t] * wsc;
        else if (r < 1537) v = wv[((long)l * 513 + (r - 1024)) * 513 + t] * wsc;
    }
    wcat[idx] = f2bf(v);
}

__global__ __launch_bounds__(256) void k_prep_wo(
    const float* __restrict__ wo, u16* __restrict__ wop)
{
    long idx = (long)blockIdx.x * 256 + threadIdx.x;
    if (idx >= 4L * P * P) return;
    int u = (int)(idx % P);
    long rem = idx / P;
    int t = (int)(rem % P);
    int l = (int)(rem / P);
    float v = (t < 513 && u < 513) ? wo[((long)l * 513 + t) * 513 + u] : 0.f;
    wop[idx] = f2bf(v);
}

__global__ __launch_bounds__(256) void k_prep_sums(
    const float* __restrict__ wq, const float* __restrict__ wk,
    const float* __restrict__ wv, const float* __restrict__ ln1w,
    const float* __restrict__ ln1b, float* __restrict__ s1, float* __restrict__ s2)
{
    int id = blockIdx.x * 4 + (threadIdx.x >> 6);
    int lane = threadIdx.x & 63;
    int l = id / NQK, r = id % NQK;
    float a1 = 0.f, a2 = 0.f;
    for (int t = lane; t < 513; t += 64) {
        float wc = 0.f;
        if (r < 512)       wc = wq[((long)l * 512 + r) * 513 + t];
        else if (r < 1024) wc = wk[((long)l * 512 + (r - 512)) * 513 + t];
        else if (r < 1537) wc = wv[((long)l * 513 + (r - 1024)) * 513 + t];
        a1 += ln1w[l * 513 + t] * wc;
        a2 += ln1b[l * 513 + t] * wc;
    }
    a1 = wredsum(a1); a2 = wredsum(a2);
    if (lane == 0) { s1[id] = a1; s2[id] = a2; }
}

// ---------------------------------------------------------------------------
// LN2: tok = LN(z)*w + b. z cols >= 512 are NOT read (z-GEMM is N=512 now);
// the t=512 value is synthesized: zc = 0.1*znum/(denom+eps) + tok_old[512].
__global__ __launch_bounds__(256) void k_ln2(
    const u16* __restrict__ z, u16* __restrict__ tok,
    const float* __restrict__ w, const float* __restrict__ bia,
    float* __restrict__ meanb, float* __restrict__ rstdb,
    const float* __restrict__ znum, const float* __restrict__ denomb)
{
    long row = (long)blockIdx.x * 4 + (threadIdx.x >> 6);
    int lane = threadIdx.x & 63;
    const u16* zp = z + row * P;
    u16* tp = tok + row * P;
    u16x8 a0 = *(const u16x8*)(zp + lane * 8);
    float zc = 0.f;
    if (lane == 0)
        zc = 0.1f * znum[row] / (denomb[row] + 1e-6f) + bf2f(tp[512]);
    float v0[8], v1[8];
#pragma unroll
    for (int j = 0; j < 8; j++) v0[j] = bf2f(a0[j]);
#pragma unroll
    for (int j = 0; j < 8; j++) v1[j] = 0.f;
    v1[0] = zc;
    float s = 0.f, sq = 0.f;
#pragma unroll
    for (int j = 0; j < 8; j++) { s += v0[j]; sq += v0[j] * v0[j]; }
#pragma unroll
    for (int j = 0; j < 8; j++) { s += v1[j]; sq += v1[j] * v1[j]; }
    s = wredsum(s); sq = wredsum(sq);
    float mean = s * (1.f / 513.f);
    float var = sq * (1.f / 513.f) - mean * mean;
    float rstd = 1.f / sqrtf(var + 1e-5f);
    float so = 0.f, so2 = 0.f;
    u16x8 o0;
    float of0[8];
#pragma unroll
    for (int j = 0; j < 8; j++) {
        int t = lane * 8 + j;
        of0[j] = (v0[j] - mean) * rstd * w[t] + bia[t];
        so += of0[j]; so2 += of0[j] * of0[j];
        o0[j] = f2bf(of0[j]);
    }
    float of1[8];
#pragma unroll
    for (int j = 0; j < 8; j++) {
        int t = 512 + lane * 8 + j;
        float ov = 0.f;
        if (lane < 8 && t < 513) ov = (v1[j] - mean) * rstd * w[t] + bia[t];
        of1[j] = ov;
        so += ov; so2 += ov * ov;
    }
    so = wredsum(so); so2 = wredsum(so2);
    *(u16x8*)(tp + lane * 8) = o0;
    if (lane < 8) {
        u16x8 o1;
#pragma unroll
        for (int j = 0; j < 8; j++) o1[j] = f2bf(of1[j]);
        *(u16x8*)(tp + 512 + lane * 8) = o1;
    }
    if (lane == 0) {
        float m2 = so * (1.f / 513.f);
        float v2 = so2 * (1.f / 513.f) - m2 * m2;
        meanb[row] = m2;
        rstdb[row] = 1.f / sqrtf(v2 + 1e-5f);
    }
}

// ---------------------------------------------------------------------------
// Fused qknorm + K-transpose + ksum + v512 matvec. One block = 64 rows.
// v512sum[b][h] += sum_n Kp[n][h] * V[n][512]  (vt row 512, f32 atomics).
__global__ __launch_bounds__(256) void k_qkt(
    u16* __restrict__ qkv, u16* __restrict__ kpt,
    float* __restrict__ ksum, float* __restrict__ v512sum,
    const u16* __restrict__ vt, const float* __restrict__ scale, int l)
{
    long row0 = (long)blockIdx.x * 64;
    int b = (int)(row0 >> 11);
    int nloc = (int)(row0 & 2047);
    int tid = threadIdx.x, lane = tid & 63, w = tid >> 6;
    float s = log1pf(expf(scale[l]));
    __shared__ u16 Kp[64][520];
    __shared__ u16 T2[64 * 80];

#pragma unroll 4
    for (int i = 0; i < 16; i++) {
        int rl = w * 16 + i;
        u16* rp = qkv + (row0 + rl) * NQK;
        u16x8 q8 = *(const u16x8*)(rp + lane * 8);
        u16x8 k8 = *(const u16x8*)(rp + 512 + lane * 8);
        float qf[8], kf[8];
        float sq = 0.f, sk = 0.f;
#pragma unroll
        for (int j = 0; j < 8; j++) { qf[j] = bf2f(q8[j]); sq += qf[j] * qf[j]; }
#pragma unroll
        for (int j = 0; j < 8; j++) { kf[j] = bf2f(k8[j]); sk += kf[j] * kf[j]; }
        sq = wredsum(sq); sk = wredsum(sk);
        float rnq = 1.f / fmaxf(sqrtf(sq), 1e-12f);
        float rnk = 1.f / fmaxf(sqrtf(sk), 1e-12f);
        u16x8 o, kk;
#pragma unroll
        for (int j = 0; j < 8; j++) {
            float q = qf[j] * rnq;
            float qp = (q > 0.f) ? (q + 1.f) : expf(q);
            o[j] = f2bf(qp * s);
            float kv = kf[j] * rnk;
            kv = (kv > 0.f) ? (kv + 1.f) : expf(kv);
            kk[j] = f2bf(kv);
        }
        *(u16x8*)(rp + lane * 8) = o;
        *(u16x8*)&Kp[rl][lane * 8] = kk;
    }
    __syncthreads();

    // V[:,512] values for this block's 64 tokens (per-thread 16, hoisted)
    const u16* vrow = vt + ((long)b * VTROWS + 512) * 2048 + nloc + (tid & 3) * 16;
    u16x8 va = *(const u16x8*)vrow;
    u16x8 vb = *(const u16x8*)(vrow + 8);
    float vf[16];
#pragma unroll
    for (int j = 0; j < 8; j++) { vf[j] = bf2f(va[j]); vf[8 + j] = bf2f(vb[j]); }

    int r = tid >> 2;
    int c0 = (tid & 3) * 16;
    for (int ct = 0; ct < 8; ct++) {
        u16x8 a = *(const u16x8*)&Kp[r][ct * 64 + c0];
        u16x8 d = *(const u16x8*)&Kp[r][ct * 64 + c0 + 8];
#pragma unroll
        for (int j = 0; j < 8; j++) T2[(c0 + j) * 80 + r] = a[j];
#pragma unroll
        for (int j = 0; j < 8; j++) T2[(c0 + 8 + j) * 80 + r] = d[j];
        __syncthreads();
        u16x8 w0 = *(const u16x8*)&T2[r * 80 + c0];
        u16x8 w1 = *(const u16x8*)&T2[r * 80 + c0 + 8];
        u16* dst = kpt + ((long)(b * 512 + ct * 64 + r)) * 2048 + nloc + c0;
        *(u16x8*)dst = w0;
        *(u16x8*)(dst + 8) = w1;
        float part = 0.f, p2 = 0.f;
#pragma unroll
        for (int j = 0; j < 8; j++) {
            float k0 = bf2f(w0[j]), k1 = bf2f(w1[j]);
            part += k0 + k1;
            p2 += k0 * vf[j] + k1 * vf[8 + j];
        }
        part += __shfl_xor(part, 1, 64);
        part += __shfl_xor(part, 2, 64);
        p2 += __shfl_xor(p2, 1, 64);
        p2 += __shfl_xor(p2, 2, 64);
        if ((tid & 3) == 0) {
            atomicAdd(&ksum[(long)b * 512 + ct * 64 + r], part);
            atomicAdd(&v512sum[(long)b * 512 + ct * 64 + r], p2);
        }
        __syncthreads();
    }
}

// kvh[b][h][512] = v512sum[b][h] (bf16) — for w2t GEMM's rank-1 read.
__global__ __launch_bounds__(512) void k_v512(
    const float* __restrict__ v512sum, u16* __restrict__ kvh)
{
    int b = blockIdx.x, h = threadIdx.x;
    kvh[((long)b * 512 + h) * KVLD + 512] = f2bf(v512sum[(long)b * 512 + h]);
}

// ---------------------------------------------------------------------------
// denom[row] = Qp[row].ksum[b];  znum[row] = Qp[row].w2t[b][512][:]
__global__ __launch_bounds__(256) void k_denom(
    const u16* __restrict__ qkv, const float* __restrict__ ksum,
    const u16* __restrict__ w2t, float* __restrict__ denom,
    float* __restrict__ znum)
{
    long row = (long)blockIdx.x * 4 + (threadIdx.x >> 6);
    int lane = threadIdx.x & 63;
    int b = (int)(row >> 11);
    u16x8 q = *(const u16x8*)(qkv + row * NQK + lane * 8);
    const float* ks = ksum + (long)b * 512 + lane * 8;
    u16x8 w8 = *(const u16x8*)(w2t + (long)b * 576 * 512 + 512 * 512 + lane * 8);
    float acc = 0.f, acc2 = 0.f;
#pragma unroll
    for (int j = 0; j < 8; j++) {
        float qf = bf2f(q[j]);
        acc += qf * ks[j];
        acc2 += qf * bf2f(w8[j]);
    }
    acc = wredsum(acc);
    acc2 = wredsum(acc2);
    if (lane == 0) { denom[row] = acc; znum[row] = acc2; }
}

__global__ void k_predict(const u16* __restrict__ tok, const float* __restrict__ pw,
                          float* __restrict__ out)
{
    int b = blockIdx.x;
    int lane = threadIdx.x;
    const u16* rp = tok + ((long)b * 2048 + 2047) * P;
    float acc = 0.f;
    for (int t = lane; t < 513; t += 64) acc += bf2f(rp[t]) * pw[t];
    acc = wredsum(acc);
    if (lane == 0) out[b] = acc;
}

// ---------------------------------------------------------------------------
// GEMM C[m][n] = sum_{k<K} A[m][k]*Bt[n][k]  (+ A[m][K]*Bt[n][K] if r1).
// 128x128 tile, BK=64, 4 waves. 1-D grid, bijective XCD-chunked swizzle.
// T2 LDS XOR-swizzle (both-sides): pre-swizzled global source column for
// global_load_lds + matching XOR on ds_read_b128 fragment reads.
__global__ __launch_bounds__(256) void k_gemm_bt(
    const u16* __restrict__ A, const u16* __restrict__ Bt, u16* __restrict__ C,
    int M, int N, int K, int lda, int ldb, int ldc,
    long sA, long sB, long sC,
    const float* __restrict__ aux1, const float* __restrict__ aux2,
    const float* __restrict__ aux3, const float* __restrict__ aux4,
    long sAux, const u16* __restrict__ Res,
    float cscale, int mode, int r1, int padw,
    int ntm, int ntn, int nbz,
    u16* __restrict__ VT, int vtbase)
{
    int G = ntm * ntn * nbz;
    int id = blockIdx.x;
    int lin = (id & 7) * (G >> 3) + (id >> 3);
    int per = ntm * ntn;
    int bz = lin / per;
    int rem = lin - bz * per;
    int mt = rem / ntn;
    int nt = rem - mt * ntn;
    int m0 = mt * 128, n0 = nt * 128;

    A += (long)bz * sA; Bt += (long)bz * sB; C += (long)bz * sC;
    int tid = threadIdx.x, lane = tid & 63, w = tid >> 6;
    int wr = w >> 1, wc = w & 1;
    __shared__ u16 ldsbuf[2 * 128 * 64];      // Als | Bls; then Res/C tile
    u16* Als = ldsbuf;
    u16* Bls = ldsbuf + 128 * 64;
    __shared__ float auxR0[128], auxR1[128], auxA1[128];
    __shared__ float auxC0[128], auxC1[128], auxB1[128];

    if (tid < 128) {
        int gr = m0 + tid; if (gr >= M) gr = M - 1;
        float r0v = cscale, r1v = 0.f, a1v = 0.f;
        if (mode == 1) {
            const float* d1 = aux1 + (long)bz * sAux;
            r0v = cscale / (d1[gr] + 1e-6f);
        } else if (mode == 3) { r0v = aux1[gr]; r1v = aux2[gr]; }
        if (r1) a1v = bf2f(A[(long)gr * lda + K]);
        auxR0[tid] = r0v; auxR1[tid] = r1v; auxA1[tid] = a1v;
    } else {
        int t = tid - 128;
        int gc = n0 + t; if (gc >= N) gc = N - 1;
        float c0v = 0.f, c1v = 0.f, b1v = 0.f;
        if (mode == 3) { c0v = aux3[gc]; c1v = aux4[gc]; }
        if (r1) b1v = bf2f(Bt[(long)gc * ldb + K]);
        auxC0[t] = c0v; auxC1[t] = c1v; auxB1[t] = b1v;
    }

    f32x4 acc[4][4];
#pragma unroll
    for (int m = 0; m < 4; m++)
#pragma unroll
        for (int n = 0; n < 4; n++) { acc[m][n][0]=0.f; acc[m][n][1]=0.f; acc[m][n][2]=0.f; acc[m][n][3]=0.f; }

    int srow = lane >> 3;
    int scol = (lane & 7) * 8;
    int scolsw = scol ^ (srow << 3);
    int swz = (lane & 7) << 3;

    for (int k0 = 0; k0 < K; k0 += 64) {
#pragma unroll
        for (int i = 0; i < 4; i++) {
            int rt = (w * 4 + i) * 8 + srow;
            int gr = m0 + rt; gr = (gr < M) ? gr : (M - 1);
            gload_lds16(A + (long)gr * lda + k0 + scolsw, &Als[(w * 4 + i) * 512]);
        }
#pragma unroll
        for (int i = 0; i < 4; i++) {
            int rt = (w * 4 + i) * 8 + srow;
            int gc = n0 + rt; gc = (gc < N) ? gc : (N - 1);
            gload_lds16(Bt + (long)gc * ldb + k0 + scolsw, &Bls[(w * 4 + i) * 512]);
        }
        __syncthreads();
#pragma unroll
        for (int ks = 0; ks < 2; ks++) {
            u16x8 af[4], bfv[4];
#pragma unroll
            for (int m = 0; m < 4; m++) {
                int row = wr * 64 + m * 16 + (lane & 15);
                af[m] = *(const u16x8*)&Als[row * 64 + ((ks * 32 + (lane >> 4) * 8) ^ swz)];
            }
#pragma unroll
            for (int n = 0; n < 4; n++) {
                int col = wc * 64 + n * 16 + (lane & 15);
                bfv[n] = *(const u16x8*)&Bls[col * 64 + ((ks * 32 + (lane >> 4) * 8) ^ swz)];
            }
#pragma unroll
            for (int m = 0; m < 4; m++)
#pragma unroll
                for (int n = 0; n < 4; n++)
                    acc[m][n] = mfma_16x16x32_bf16(af[m], bfv[n], acc[m][n]);
        }
        __syncthreads();
    }
    // LDS (Als/Bls) now dead; reuse for Res/C tile.

    bool isvt = (VT != nullptr) && (n0 >= vtbase);

    if (Res) {
        const u16* Rp = Res + (long)bz * sC;
#pragma unroll
        for (int i = 0; i < 8; i++) {
            int lrow = i * 16 + (tid >> 4);
            int lcol = (tid & 15) * 8;
            long gr = m0 + lrow; if (gr > (long)M - 1) gr = M - 1;
            long gcol = (long)n0 + lcol;
            long mx = (long)ldc - 8; if (gcol > mx) gcol = mx;
            *(u16x8*)&ldsbuf[lrow * 128 + lcol] = *(const u16x8*)&Rp[gr * ldc + gcol];
        }
        __syncthreads();
    }

    asm volatile("s_nop 7\n\ts_nop 7" ::: );

    if (!isvt) {
        // normal pack: ldsbuf[row][col]
#pragma unroll
        for (int m = 0; m < 4; m++) {
            int lrbase = wr * 64 + m * 16 + ((lane >> 4) << 2);
#pragma unroll
            for (int n = 0; n < 4; n++) {
                int lc = wc * 64 + n * 16 + (lane & 15);
                float c0v = auxC0[lc], c1v = auxC1[lc], b1v = auxB1[lc];
#pragma unroll
                for (int r = 0; r < 4; r++) {
                    int lr = lrbase + r;
                    float wv = acc[m][n][r] + auxA1[lr] * b1v;
                    float v;
                    if (mode == 3) v = auxR1[lr] * (wv - auxR0[lr] * c0v) + c1v;
                    else {
                        v = wv * auxR0[lr];
                        if (Res) v += bf2f(ldsbuf[lr * 128 + lc]);
                    }
                    ldsbuf[lr * 128 + lc] = f2bf(v);
                }
            }
        }
        __syncthreads();

        int lcol = (tid & 15) * 8;
        int gc0 = n0 + lcol;
        bool colok = padw || (gc0 + 8 <= N);
#pragma unroll
        for (int i = 0; i < 8; i++) {
            int lrow = i * 16 + (tid >> 4);
            int gr = m0 + lrow;
            if (gr < M && colok) {
                *(u16x8*)&C[(long)gr * ldc + gc0] = *(const u16x8*)&ldsbuf[lrow * 128 + lcol];
            }
        }
    } else {
        // V-direct: pack transposed + XOR-swizzled: ldsbuf[u][token^((u&7)<<3)]
        // (includes rank-1 term when r1 — required for K=512+r1 QKV)
        int u0 = n0 - vtbase;
        int b = m0 >> 11;
        int nloc = m0 & 2047;
#pragma unroll
        for (int m = 0; m < 4; m++) {
            int lrbase = wr * 64 + m * 16 + ((lane >> 4) << 2);
#pragma unroll
            for (int n = 0; n < 4; n++) {
                int lc = wc * 64 + n * 16 + (lane & 15);
                float c0v = auxC0[lc], c1v = auxC1[lc], b1v = auxB1[lc];
#pragma unroll
                for (int r = 0; r < 4; r++) {
                    int lr = lrbase + r;
                    float wv = acc[m][n][r] + auxA1[lr] * b1v;
                    float v = (mode == 3) ? (auxR1[lr] * (wv - auxR0[lr] * c0v) + c1v)
                                          : (wv * auxR0[lr]);
                    ldsbuf[lc * 128 + (lr ^ ((lc & 7) << 3))] = f2bf(v);
                }
            }
        }
        __syncthreads();

        int nc = (tid & 15) * 8;          // token offset, 8-contiguous
        const u16x8 ones = {0x3F80,0x3F80,0x3F80,0x3F80,0x3F80,0x3F80,0x3F80,0x3F80};
#pragma unroll
        for (int i = 0; i < 8; i++) {
            int ur = i * 16 + (tid >> 4);
            int u = u0 + ur;
            if (u < VTROWS) {
                u16x8 vv;
                if (u == 513) vv = ones;
                else vv = *(const u16x8*)&ldsbuf[ur * 128 + (nc ^ ((ur & 7) << 3))];
                *(u16x8*)&VT[((long)b * VTROWS + u) * 2048 + nloc + nc] = vv;
            }
        }
    }
}

// ---------------------------------------------------------------------------
extern "C" void kernel_launch(void* const* d_in, const int* in_sizes, int n_in,
                              void* d_out, int out_size, void* d_ws, size_t ws_size,
                              hipStream_t stream)
{
    const float* xs    = (const float*)d_in[0];
    const float* ys    = (const float*)d_in[1];
    const float* qx    = (const float*)d_in[2];
    const float* Wq    = (const float*)d_in[3];
    const float* Wk    = (const float*)d_in[4];
    const float* Wv    = (const float*)d_in[5];
    const float* Wo    = (const float*)d_in[6];
    const float* ln1w  = (const float*)d_in[7];
    const float* ln1b  = (const float*)d_in[8];
    const float* ln2w  = (const float*)d_in[9];
    const float* ln2b  = (const float*)d_in[10];
    const float* scale = (const float*)d_in[11];
    const float* predw = (const float*)d_in[12];
    float* out = (float*)d_out;

    char* ws = (char*)d_ws;
    u16*   tok   = (u16*)(ws + 0L);              // 150,994,944
    u16*   buf1  = (u16*)(ws + 150994944L);      // vt (ends 285,736,960) + tail
    u16*   qkv   = (u16*)(ws + 301989888L);      // 436,207,616
    u16*   kpt   = (u16*)(ws + 738197504L);      // 134,217,728  Kp^T / w2t
    u16*   kvh   = (u16*)(ws + 872415232L);      //  41,943,040
    float* denom = (float*)(ws + 914358272L);
    float* meanb = (float*)(ws + 914882560L);
    float* rstdb = (float*)(ws + 915406848L);
    float* ksum  = (float*)(ws + 915931136L);
    u16*   wcat  = (u16*)(ws + 916062208L);
    u16*   wop   = (u16*)(ws + 923729920L);
    float* s1    = (float*)(ws + 926384128L);
    float* s2    = (float*)(ws + 926410752L);
    float* v512s = (float*)(ws + 285736960L);    // buf1 tail: 64*512*4
    float* znum  = (float*)(ws + 285868032L);    // buf1 tail: 131072*4
    u16*   w2t   = kpt;

    k_build_tokens<<<32768, 256, 0, stream>>>(xs, ys, qx, tok, meanb, rstdb);
    {
        long n1 = 4L * NQK * P;
        k_prep_wcat<<<(int)((n1 + 255) / 256), 256, 0, stream>>>(Wq, Wk, Wv, ln1w, wcat);
        long n2 = 4L * P * P;
        k_prep_wo<<<(int)((n2 + 255) / 256), 256, 0, stream>>>(Wo, wop);
        k_prep_sums<<<1664, 256, 0, stream>>>(Wq, Wk, Wv, ln1w, ln1b, s1, s2);
    }

    for (int l = 0; l < 4; l++) {
        hipMemsetAsync(ksum, 0, 64 * 512 * sizeof(float), stream);
        hipMemsetAsync(v512s, 0, 64 * 512 * sizeof(float), stream);
        // QKV = LN-folded GEMM; K=512 + rank-1 (col 512); V tiles -> vt
        k_gemm_bt<<<13312, 256, 0, stream>>>(tok, wcat + (long)l * NQK * P, qkv,
            131072, NQK, 512, P, P, NQK, 0, 0, 0,
            meanb, rstdb, s1 + l * NQK, s2 + l * NQK, 0, nullptr,
            1.f, 3, 1, 0, 1024, 13, 1,
            buf1, 1024);
        // fused: Qp in place + Kp^T + ksum + v512 matvec (atomics)
        k_qkt<<<2048, 256, 0, stream>>>(qkv, kpt, ksum, v512s, buf1, scale, l);
        // kvh[b][h][u] = sum_n Kp[n][h] V[n][u], u<512 (4 clean N-tiles)
        k_gemm_bt<<<1024, 256, 0, stream>>>(kpt, buf1, kvh,
            512, 512, 2048, 2048, 2048, KVLD,
            512L * 2048, (long)VTROWS * 2048, 512L * KVLD,
            nullptr, nullptr, nullptr, nullptr, 0, nullptr, 1.f, 0, 0, 1,
            4, 4, 64, nullptr, 1 << 30);
        // kvh col 512 from the k_qkt matvec
        k_v512<<<64, 512, 0, stream>>>(v512s, kvh);
        // w2t[b][t][h] = sum_{u<=512} Wo[t][u] kvh[b][h][u]  (K=512 + rank-1)
        k_gemm_bt<<<1280, 256, 0, stream>>>(wop + (long)l * P * P, kvh, w2t,
            576, 512, 512, P, KVLD, 512,
            0, 512L * KVLD, 576L * 512,
            nullptr, nullptr, nullptr, nullptr, 0, nullptr, 1.f, 0, 1, 0,
            5, 4, 64, nullptr, 1 << 30);
        // denom + z-col-512 numerator (needs w2t row 512)
        k_denom<<<32768, 256, 0, stream>>>(qkv, ksum, w2t, denom, znum);
        // z[:, 0:512] = 0.1*(Qp @ w2t^T)/(denom+eps) + tok  (4 clean N-tiles)
        k_gemm_bt<<<4096, 256, 0, stream>>>(qkv, w2t, buf1,
            2048, 512, 512, NQK, 512, P,
            2048L * NQK, 576L * 512, 2048L * P,
            denom, nullptr, nullptr, nullptr, 2048, tok,
            0.1f, 1, 0, 0, 16, 4, 64, nullptr, 1 << 30);
        // tok = LN2(z) + next-layer stats; z col 512 synthesized from znum
        k_ln2<<<32768, 256, 0, stream>>>(buf1, tok, ln2w + l * 513, ln2b + l * 513,
                                         meanb, rstdb, znum, denom);
    }
    k_predict<<<64, 64, 0, stream>>>(tok, predw, out);
}